// Round 1
// baseline (2600.520 us; speedup 1.0000x reference)
//
#include <hip/hip_runtime.h>
#include <hip/hip_bf16.h>
#include <math.h>

#define HGRID(n, b) (((n) + (b) - 1) / (b))

// ---------------- CSR build ----------------

__global__ void count_kernel(const int* __restrict__ dst, int* __restrict__ cnt, int E) {
    int e = blockIdx.x * 256 + threadIdx.x;
    if (e < E) atomicAdd(&cnt[dst[e]], 1);
}

__global__ void scan_kernel(const int* __restrict__ cnt, int* __restrict__ offs, int N) {
    __shared__ int sh[1024];
    int t = threadIdx.x;
    int chunk = (N + 1023) >> 10;
    int lo = t * chunk;
    int hi = min(lo + chunk, N);
    int s = 0;
    for (int i = lo; i < hi; ++i) s += cnt[i];
    sh[t] = s;
    __syncthreads();
    for (int d = 1; d < 1024; d <<= 1) {
        int v = (t >= d) ? sh[t - d] : 0;
        __syncthreads();
        sh[t] += v;
        __syncthreads();
    }
    int run = (t == 0) ? 0 : sh[t - 1];
    for (int i = lo; i < hi; ++i) { offs[i] = run; run += cnt[i]; }
    if (t == 1023) offs[N] = sh[1023];
}

__global__ void fill_kernel(const int* __restrict__ src, const int* __restrict__ dst,
                            const int* __restrict__ offs, int* __restrict__ cur,
                            int* __restrict__ elist, int E) {
    int e = blockIdx.x * 256 + threadIdx.x;
    if (e < E) {
        int d = dst[e];
        int p = offs[d] + atomicAdd(&cur[d], 1);
        elist[p] = src[e];
    }
}

__global__ void dinv_kernel(const int* __restrict__ cnt, float* __restrict__ dinv, int N) {
    int n = blockIdx.x * 256 + threadIdx.x;
    if (n < N) dinv[n] = rsqrtf((float)cnt[n] + 1.0f);
}

// ---------------- tall-skinny linear: out[N,128] = A[N,K] @ W[K,128] (+b) (+relu) ----------------

template<int K>
__global__ __launch_bounds__(256) void linear_kernel(
    const float* __restrict__ A, int a_stride,
    const float* __restrict__ W, const float* __restrict__ bias,
    float* __restrict__ out, int o_stride, int N, int act)
{
    constexpr int KC = (K < 64) ? K : 64;
    __shared__ float xs[16][K];
    __shared__ float ws[KC][128];
    const int tid  = threadIdx.x;
    const int row0 = blockIdx.x * 16;

    #pragma unroll
    for (int i = 0; i < (16 * K) / 256; ++i) {
        int idx = tid + i * 256;
        int r  = idx / K;
        int cc = idx % K;
        int gr = row0 + r;
        xs[r][cc] = (gr < N) ? A[(long)gr * a_stride + cc] : 0.f;
    }

    const int c  = tid & 127;
    const int rh = tid >> 7;
    float acc[8];
    #pragma unroll
    for (int r = 0; r < 8; ++r) acc[r] = 0.f;

    for (int k0 = 0; k0 < K; k0 += KC) {
        #pragma unroll
        for (int i = 0; i < (KC * 128) / 256; ++i) {
            int idx = tid + i * 256;
            int kk = idx >> 7;
            int cc = idx & 127;
            ws[kk][cc] = W[(k0 + kk) * 128 + cc];
        }
        __syncthreads();
        #pragma unroll
        for (int kk = 0; kk < KC; kk += 4) {
            float w0 = ws[kk + 0][c];
            float w1 = ws[kk + 1][c];
            float w2 = ws[kk + 2][c];
            float w3 = ws[kk + 3][c];
            #pragma unroll
            for (int r = 0; r < 8; ++r) {
                float4 xv = *(const float4*)&xs[r * 2 + rh][k0 + kk];
                acc[r] += xv.x * w0 + xv.y * w1 + xv.z * w2 + xv.w * w3;
            }
        }
        __syncthreads();
    }

    float bv = bias ? bias[c] : 0.f;
    #pragma unroll
    for (int r = 0; r < 8; ++r) {
        int gr = row0 + r * 2 + rh;
        if (gr < N) {
            float v = acc[r] + bv;
            if (act) v = fmaxf(v, 0.f);
            out[(long)gr * o_stride + c] = v;
        }
    }
}

// ---------------- graph aggregation (gather, CSR) ----------------

// h1[n] = relu(y[n] + sum_{src in N(n)} y[src] + b1)
__global__ void gin_gather(const float* __restrict__ y, const int* __restrict__ offs,
                           const int* __restrict__ elist, const float* __restrict__ b1,
                           float* __restrict__ h1, int N) {
    int n = blockIdx.x;
    int c = threadIdx.x;   // 128
    float acc = y[(long)n * 128 + c];
    int s0 = offs[n], s1 = offs[n + 1];
    for (int j = s0; j < s1; ++j) {
        int s = elist[j];
        acc += y[(long)s * 128 + c];
    }
    h1[(long)n * 128 + c] = fmaxf(acc + b1[c], 0.f);
}

// xc[n][128+c] = tanh( sum enorm*hs[src] + hs[n]*dinv[n]^2 + b )
__global__ void gcn_gather(const float* __restrict__ hs, const int* __restrict__ offs,
                           const int* __restrict__ elist, const float* __restrict__ dinv,
                           const float* __restrict__ gcn_b, float* __restrict__ xc, int N) {
    int n = blockIdx.x;
    int c = threadIdx.x;   // 128
    float di = dinv[n];
    float acc = 0.f;
    int s0 = offs[n], s1 = offs[n + 1];
    for (int j = s0; j < s1; ++j) {
        int s = elist[j];
        acc += hs[(long)s * 128 + c] * (dinv[s] * di);
    }
    float v = acc + hs[(long)n * 128 + c] * di * di + gcn_b[c];
    xc[(long)n * 256 + 128 + c] = tanhf(v);
}

// ---------------- pooling (batch is sorted) ----------------

__global__ void pool_kernel(const float* __restrict__ xh, const int* __restrict__ batch,
                            float* __restrict__ g, int N) {
    int c  = threadIdx.x;        // 128
    int n0 = blockIdx.x * 128;
    if (n0 >= N) return;
    int n1 = min(n0 + 128, N);
    int curg = batch[n0];
    float acc = 0.f;
    for (int n = n0; n < n1; ++n) {
        int b = batch[n];
        if (b != curg) {
            atomicAdd(&g[(long)curg * 128 + c], acc);
            acc = 0.f;
            curg = b;
        }
        acc += xh[(long)n * 128 + c];
    }
    atomicAdd(&g[(long)curg * 128 + c], acc);
}

// ---------------- head: relu(g@post_w+post_b) @ ro_w + ro_b -> log_softmax ----------------

__global__ void head_kernel(const float* __restrict__ g, const float* __restrict__ post_w,
                            const float* __restrict__ post_b, const float* __restrict__ ro_w,
                            const float* __restrict__ ro_b, float* __restrict__ out, int C) {
    __shared__ float row[128];
    __shared__ float g2[128];
    __shared__ float lg[16];
    __shared__ float s_lse;
    int gi = blockIdx.x;
    int c  = threadIdx.x;   // 128
    row[c] = g[(long)gi * 128 + c];
    __syncthreads();
    float acc = post_b[c];
    for (int k = 0; k < 128; ++k) acc += row[k] * post_w[k * 128 + c];
    g2[c] = fmaxf(acc, 0.f);
    __syncthreads();
    if (c < C) {
        float a = ro_b[c];
        for (int k = 0; k < 128; ++k) a += g2[k] * ro_w[k * C + c];
        lg[c] = a;
    }
    __syncthreads();
    if (c == 0) {
        float m = lg[0];
        for (int i = 1; i < C; ++i) m = fmaxf(m, lg[i]);
        float sum = 0.f;
        for (int i = 0; i < C; ++i) sum += expf(lg[i] - m);
        s_lse = m + logf(sum);
    }
    __syncthreads();
    if (c < C) out[(long)gi * C + c] = lg[c] - s_lse;
}

// ---------------- launch ----------------

extern "C" void kernel_launch(void* const* d_in, const int* in_sizes, int n_in,
                              void* d_out, int out_size, void* d_ws, size_t ws_size,
                              hipStream_t stream) {
    const float* x      = (const float*)d_in[0];
    const float* s_in   = (const float*)d_in[1];
    const int*   ei     = (const int*)d_in[2];
    const int*   batch  = (const int*)d_in[3];
    const float* pre_w  = (const float*)d_in[4];
    const float* pre_b  = (const float*)d_in[5];
    const float* emb_w  = (const float*)d_in[6];
    const float* emb_b  = (const float*)d_in[7];
    const float* gin_w1 = (const float*)d_in[8];
    const float* gin_b1 = (const float*)d_in[9];
    const float* gin_w2 = (const float*)d_in[10];
    const float* gin_b2 = (const float*)d_in[11];
    const float* gcn_w  = (const float*)d_in[12];
    const float* gcn_b  = (const float*)d_in[13];
    const float* whp_w  = (const float*)d_in[14];
    const float* whp_b  = (const float*)d_in[15];
    const float* post_w = (const float*)d_in[16];
    const float* post_b = (const float*)d_in[17];
    const float* ro_w   = (const float*)d_in[18];
    const float* ro_b   = (const float*)d_in[19];

    const int H = 128;
    const int N = in_sizes[0] / 128;      // F_IN = 128
    const int E = in_sizes[2] / 2;
    const int C = in_sizes[19];
    const int G = out_size / C;
    const int L = in_sizes[9] / H;        // gin_b1 is (L,H)

    const int* srcv = ei;
    const int* dstv = ei + E;

    // workspace layout (floats then ints)
    float* xc   = (float*)d_ws;                     // [N,256] concat(x,s)
    float* y    = xc   + (size_t)N * 256;           // [N,128] xc@gin_w1 ; reused for whp output
    float* hs   = y    + (size_t)N * 128;           // [N,128]
    float* h1   = hs   + (size_t)N * 128;           // [N,128]
    float* dinv = h1   + (size_t)N * 128;           // [N]
    float* gbuf = dinv + N;                         // [G,128]
    int*   cnt   = (int*)(gbuf + (size_t)G * 128);  // [N]
    int*   offs  = cnt  + N;                        // [N+1]
    int*   cur   = offs + (N + 1);                  // [N]
    int*   elist = cur  + N;                        // [E] src ids grouped by dst

    hipMemsetAsync(cnt, 0, (size_t)N * sizeof(int), stream);
    hipMemsetAsync(cur, 0, (size_t)N * sizeof(int), stream);
    hipMemsetAsync(gbuf, 0, (size_t)G * 128 * sizeof(float), stream);

    count_kernel<<<HGRID(E, 256), 256, 0, stream>>>(dstv, cnt, E);
    scan_kernel<<<1, 1024, 0, stream>>>(cnt, offs, N);
    fill_kernel<<<HGRID(E, 256), 256, 0, stream>>>(srcv, dstv, offs, cur, elist, E);
    dinv_kernel<<<HGRID(N, 256), 256, 0, stream>>>(cnt, dinv, N);

    const int lb = HGRID(N, 16);
    // pre / embedding into xc = [x | s]
    linear_kernel<128><<<lb, 256, 0, stream>>>(x, 128, pre_w, pre_b, xc, 256, N, 0);
    linear_kernel<16><<<lb, 256, 0, stream>>>(s_in, 16, emb_w, emb_b, xc + 128, 256, N, 0);

    for (int i = 0; i < L; ++i) {
        // y = xc @ gin_w1[i]   (bias folded into gather)
        linear_kernel<256><<<lb, 256, 0, stream>>>(xc, 256, gin_w1 + (size_t)i * 256 * 128,
                                                   nullptr, y, 128, N, 0);
        // hs = s @ gcn_w[i]
        linear_kernel<128><<<lb, 256, 0, stream>>>(xc + 128, 256, gcn_w + (size_t)i * 128 * 128,
                                                   nullptr, hs, 128, N, 0);
        // h1 = relu(y + A@y + b1)
        gin_gather<<<N, 128, 0, stream>>>(y, offs, elist, gin_b1 + i * H, h1, N);
        // x half of xc = relu(h1 @ gin_w2[i] + b2)
        linear_kernel<128><<<lb, 256, 0, stream>>>(h1, 128, gin_w2 + (size_t)i * 128 * 128,
                                                   gin_b2 + i * H, xc, 256, N, 1);
        // s half of xc = tanh(Anorm@hs + hs*selfnorm + b)
        gcn_gather<<<N, 128, 0, stream>>>(hs, offs, elist, dinv, gcn_b + i * H, xc, N);
    }

    // xh = xc @ whp_w + whp_b   (into y, free now)
    linear_kernel<256><<<lb, 256, 0, stream>>>(xc, 256, whp_w, whp_b, y, 128, N, 0);

    pool_kernel<<<HGRID(N, 128), 128, 0, stream>>>(y, batch, gbuf, N);
    head_kernel<<<G, 128, 0, stream>>>(gbuf, post_w, post_b, ro_w, ro_b, (float*)d_out, C);
}

// Round 2
// 731.185 us; speedup vs baseline: 3.5566x; 3.5566x over previous
//
#include <hip/hip_runtime.h>
#include <math.h>

typedef __attribute__((ext_vector_type(8))) short short8;
typedef __attribute__((ext_vector_type(4))) float f32x4;
typedef unsigned int uint;
typedef unsigned short ushort;

#define HGRID(n, b) (((n) + (b) - 1) / (b))

__device__ __forceinline__ ushort f2bu(float f) {
    uint x = __builtin_bit_cast(uint, f);
    x = (x + 0x7fffu + ((x >> 16) & 1u)) >> 16;
    return (ushort)x;
}
__device__ __forceinline__ float bu2f(uint u) {
    return __builtin_bit_cast(float, u << 16);
}
__device__ __forceinline__ uint packbf(float a, float b) {
    return (uint)f2bu(a) | ((uint)f2bu(b) << 16);
}

// ---------------- CSR build ----------------

__global__ void count_kernel(const int* __restrict__ dst, int* __restrict__ cnt, int E) {
    int e = blockIdx.x * 256 + threadIdx.x;
    if (e < E) atomicAdd(&cnt[dst[e]], 1);
}

__global__ void scan_kernel(const int* __restrict__ cnt, int* __restrict__ offs, int N) {
    __shared__ int sh[1024];
    int t = threadIdx.x;
    int chunk = (N + 1023) >> 10;
    int lo = t * chunk;
    int hi = min(lo + chunk, N);
    int s = 0;
    for (int i = lo; i < hi; ++i) s += cnt[i];
    sh[t] = s;
    __syncthreads();
    for (int d = 1; d < 1024; d <<= 1) {
        int v = (t >= d) ? sh[t - d] : 0;
        __syncthreads();
        sh[t] += v;
        __syncthreads();
    }
    int run = (t == 0) ? 0 : sh[t - 1];
    for (int i = lo; i < hi; ++i) { offs[i] = run; run += cnt[i]; }
    if (t == 1023) offs[N] = sh[1023];
}

__global__ void fill_kernel(const int* __restrict__ src, const int* __restrict__ dst,
                            const int* __restrict__ offs, int* __restrict__ cur,
                            int* __restrict__ elist, int E) {
    int e = blockIdx.x * 256 + threadIdx.x;
    if (e < E) {
        int d = dst[e];
        int p = offs[d] + atomicAdd(&cur[d], 1);
        elist[p] = src[e];
    }
}

__global__ void dinv_kernel(const int* __restrict__ cnt, float* __restrict__ dinv, int N) {
    int n = blockIdx.x * 256 + threadIdx.x;
    if (n < N) dinv[n] = rsqrtf((float)cnt[n] + 1.0f);
}

// ---------------- fp32 -> bf16 conversion ----------------

__global__ void f2b_kernel(const float* __restrict__ in, ushort* __restrict__ out, long n) {
    long i = ((long)blockIdx.x * 256 + threadIdx.x) * 4;
    if (i + 3 < n) {
        float4 v = *(const float4*)(in + i);
        ushort4 o;
        o.x = f2bu(v.x); o.y = f2bu(v.y); o.z = f2bu(v.z); o.w = f2bu(v.w);
        *(ushort4*)(out + i) = o;
    } else {
        for (; i < n; ++i) out[i] = f2bu(in[i]);
    }
}

// W[K][128] fp32 -> Wt[128][KPAD] bf16 (zero-padded beyond K)
__global__ void twb_kernel(const float* __restrict__ W, ushort* __restrict__ Wt,
                           int K, int KPAD) {
    int idx = blockIdx.x * 256 + threadIdx.x;
    if (idx >= 128 * KPAD) return;
    int c = idx / KPAD;
    int k = idx % KPAD;
    Wt[(long)c * KPAD + k] = (k < K) ? f2bu(W[(long)k * 128 + c]) : (ushort)0;
}

// ---------------- bf16 MFMA linear: out[N,128] = A[N,K] @ W[K,128] ----------------
// A bf16 row-major (stride a_stride), Wt bf16 [128][KPAD] transposed+padded.
// BM=64 (2 waves x 32 rows), BK=min(KPAD,64). fp32 accum, bias+act fused, bf16 out.

template<int KPAD>
__global__ __launch_bounds__(128) void linear_mfma(
    const ushort* __restrict__ A, int a_stride, int Kreal,
    const ushort* __restrict__ Wt, const float* __restrict__ bias,
    ushort* __restrict__ out, int o_stride, int N, int act)
{
    constexpr int BK  = (KPAD < 64) ? KPAD : 64;
    constexpr int LDK = BK + 8;          // +16B pad -> 2-way bank aliasing (free)
    constexpr int CB  = BK / 8;          // 16B chunks per row
    __shared__ __align__(16) ushort LA[64][LDK];
    __shared__ __align__(16) ushort LB[128][LDK];

    const int tid  = threadIdx.x;
    const int l    = tid & 63;
    const int wid  = tid >> 6;
    const int row0 = blockIdx.x * 64;
    const int l15  = l & 15;
    const int lhi  = l >> 4;

    f32x4 acc[2][8];
    #pragma unroll
    for (int m = 0; m < 2; ++m)
        #pragma unroll
        for (int n = 0; n < 8; ++n) acc[m][n] = (f32x4){0.f, 0.f, 0.f, 0.f};

    for (int k0 = 0; k0 < KPAD; k0 += BK) {
        __syncthreads();
        // stage A tile [64][BK]
        #pragma unroll
        for (int it = 0; it < CB / 2; ++it) {
            int idx = it * 128 + tid;
            int r = idx / CB, ch = idx % CB;
            int gr = row0 + r, col = k0 + ch * 8;
            uint4 v = {0u, 0u, 0u, 0u};
            if (gr < N && col < Kreal)
                v = *(const uint4*)(A + (long)gr * a_stride + col);
            *(uint4*)&LA[r][ch * 8] = v;
        }
        // stage B tile [128][BK] from Wt (always in-bounds, pre-zero-padded)
        #pragma unroll
        for (int it = 0; it < CB; ++it) {
            int idx = it * 128 + tid;
            int c = idx / CB, ch = idx % CB;
            uint4 v = *(const uint4*)(Wt + (long)c * KPAD + k0 + ch * 8);
            *(uint4*)&LB[c][ch * 8] = v;
        }
        __syncthreads();
        #pragma unroll
        for (int kk = 0; kk < BK; kk += 32) {
            int ko = kk + lhi * 8;
            short8 a0 = *(const short8*)&LA[wid * 32 + l15][ko];
            short8 a1 = *(const short8*)&LA[wid * 32 + 16 + l15][ko];
            #pragma unroll
            for (int n = 0; n < 8; ++n) {
                short8 b = *(const short8*)&LB[n * 16 + l15][ko];
                acc[0][n] = __builtin_amdgcn_mfma_f32_16x16x32_bf16(a0, b, acc[0][n], 0, 0, 0);
                acc[1][n] = __builtin_amdgcn_mfma_f32_16x16x32_bf16(a1, b, acc[1][n], 0, 0, 0);
            }
        }
    }

    #pragma unroll
    for (int n = 0; n < 8; ++n) {
        int col = n * 16 + l15;
        float bv = bias ? bias[col] : 0.f;
        #pragma unroll
        for (int m = 0; m < 2; ++m) {
            #pragma unroll
            for (int j = 0; j < 4; ++j) {
                int row = wid * 32 + m * 16 + (lhi << 2) + j;
                int gr = row0 + row;
                if (gr < N) {
                    float v = acc[m][n][j] + bv;
                    if (act) v = fmaxf(v, 0.f);
                    out[(long)gr * o_stride + col] = f2bu(v);
                }
            }
        }
    }
}

// ---------------- fused GIN+GCN gather (wave per node, packed bf16 rows) ----------------
// h1[n]   = relu(y[n] + sum_s y[s] + b1)
// xc_s[n] = tanh(sum_s hs[s]*dinv_s*dinv_n + hs[n]*dinv_n^2 + gcn_b)

__global__ __launch_bounds__(256) void fused_gather(
    const uint* __restrict__ yp, const uint* __restrict__ hp,
    const int* __restrict__ offs, const int* __restrict__ elist,
    const float* __restrict__ dinv,
    const float* __restrict__ b1, const float* __restrict__ gb,
    uint* __restrict__ h1p, uint* __restrict__ xcp, int N)
{
    int node = blockIdx.x * 4 + (threadIdx.x >> 6);
    if (node >= N) return;
    int l = threadIdx.x & 63;
    long nbase = (long)node * 64;

    uint vy = yp[nbase + l];
    uint vh = hp[nbase + l];
    float di = dinv[node];

    float g0 = bu2f(vy & 0xffffu), g1 = bu2f(vy >> 16);
    float s0 = 0.f, s1 = 0.f;

    int j0 = offs[node], j1 = offs[node + 1];
    for (int j = j0; j < j1; ++j) {
        int s = elist[j];
        float ds = dinv[s] * di;
        uint wy = yp[(long)s * 64 + l];
        uint wh = hp[(long)s * 64 + l];
        g0 += bu2f(wy & 0xffffu);
        g1 += bu2f(wy >> 16);
        s0 += bu2f(wh & 0xffffu) * ds;
        s1 += bu2f(wh >> 16) * ds;
    }

    float2 bb = ((const float2*)b1)[l];
    g0 = fmaxf(g0 + bb.x, 0.f);
    g1 = fmaxf(g1 + bb.y, 0.f);
    h1p[nbase + l] = packbf(g0, g1);

    float dii = di * di;
    float2 gg = ((const float2*)gb)[l];
    float t0 = tanhf(s0 + bu2f(vh & 0xffffu) * dii + gg.x);
    float t1 = tanhf(s1 + bu2f(vh >> 16) * dii + gg.y);
    xcp[(long)node * 128 + 64 + l] = packbf(t0, t1);
}

// ---------------- pooling (batch sorted, bf16 input, fp32 atomics) ----------------

__global__ void pool_kernel(const ushort* __restrict__ xh, const int* __restrict__ batch,
                            float* __restrict__ g, int N) {
    int c  = threadIdx.x;        // 128
    int n0 = blockIdx.x * 128;
    if (n0 >= N) return;
    int n1 = min(n0 + 128, N);
    int curg = batch[n0];
    float acc = 0.f;
    for (int n = n0; n < n1; ++n) {
        int b = batch[n];
        if (b != curg) {
            atomicAdd(&g[(long)curg * 128 + c], acc);
            acc = 0.f;
            curg = b;
        }
        acc += bu2f((uint)xh[(long)n * 128 + c]);
    }
    atomicAdd(&g[(long)curg * 128 + c], acc);
}

// ---------------- head ----------------

__global__ void head_kernel(const float* __restrict__ g, const float* __restrict__ post_w,
                            const float* __restrict__ post_b, const float* __restrict__ ro_w,
                            const float* __restrict__ ro_b, float* __restrict__ out, int C) {
    __shared__ float row[128];
    __shared__ float g2[128];
    __shared__ float lg[16];
    __shared__ float s_lse;
    int gi = blockIdx.x;
    int c  = threadIdx.x;   // 128
    row[c] = g[(long)gi * 128 + c];
    __syncthreads();
    float acc = post_b[c];
    for (int k = 0; k < 128; ++k) acc += row[k] * post_w[k * 128 + c];
    g2[c] = fmaxf(acc, 0.f);
    __syncthreads();
    if (c < C) {
        float a = ro_b[c];
        for (int k = 0; k < 128; ++k) a += g2[k] * ro_w[k * C + c];
        lg[c] = a;
    }
    __syncthreads();
    if (c == 0) {
        float m = lg[0];
        for (int i = 1; i < C; ++i) m = fmaxf(m, lg[i]);
        float sum = 0.f;
        for (int i = 0; i < C; ++i) sum += expf(lg[i] - m);
        s_lse = m + logf(sum);
    }
    __syncthreads();
    if (c < C) out[(long)gi * C + c] = lg[c] - s_lse;
}

// ---------------- launch ----------------

extern "C" void kernel_launch(void* const* d_in, const int* in_sizes, int n_in,
                              void* d_out, int out_size, void* d_ws, size_t ws_size,
                              hipStream_t stream) {
    const float* x      = (const float*)d_in[0];
    const float* s_in   = (const float*)d_in[1];
    const int*   ei     = (const int*)d_in[2];
    const int*   batch  = (const int*)d_in[3];
    const float* pre_w  = (const float*)d_in[4];
    const float* pre_b  = (const float*)d_in[5];
    const float* emb_w  = (const float*)d_in[6];
    const float* emb_b  = (const float*)d_in[7];
    const float* gin_w1 = (const float*)d_in[8];
    const float* gin_b1 = (const float*)d_in[9];
    const float* gin_w2 = (const float*)d_in[10];
    const float* gin_b2 = (const float*)d_in[11];
    const float* gcn_w  = (const float*)d_in[12];
    const float* gcn_b  = (const float*)d_in[13];
    const float* whp_w  = (const float*)d_in[14];
    const float* whp_b  = (const float*)d_in[15];
    const float* post_w = (const float*)d_in[16];
    const float* post_b = (const float*)d_in[17];
    const float* ro_w   = (const float*)d_in[18];
    const float* ro_b   = (const float*)d_in[19];

    const int H = 128;
    const int N = in_sizes[0] / 128;
    const int E = in_sizes[2] / 2;
    const int C = in_sizes[19];
    const int G = out_size / C;
    const int L = in_sizes[9] / H;

    const int* srcv = ei;
    const int* dstv = ei + E;

    // ---- workspace layout ----
    char* p = (char*)d_ws;
    auto alloc = [&](size_t bytes) -> void* {
        void* r = (void*)p;
        p += (bytes + 255) & ~(size_t)255;
        return r;
    };
    ushort* xc  = (ushort*)alloc((size_t)N * 256 * 2);   // [N][256] = [x | s]
    ushort* y   = (ushort*)alloc((size_t)N * 128 * 2);   // gin_w1 out / whp out
    ushort* hs  = (ushort*)alloc((size_t)N * 128 * 2);
    ushort* h1  = (ushort*)alloc((size_t)N * 128 * 2);
    ushort* xb  = (ushort*)alloc((size_t)N * 128 * 2);   // x bf16
    ushort* sb  = (ushort*)alloc((size_t)N * 16 * 2);    // s bf16
    ushort* Wt_pre  = (ushort*)alloc(128 * 128 * 2);
    ushort* Wt_emb  = (ushort*)alloc(128 * 32 * 2);
    ushort* Wt_gin1 = (ushort*)alloc((size_t)L * 128 * 256 * 2);
    ushort* Wt_gin2 = (ushort*)alloc((size_t)L * 128 * 128 * 2);
    ushort* Wt_gcn  = (ushort*)alloc((size_t)L * 128 * 128 * 2);
    ushort* Wt_whp  = (ushort*)alloc(128 * 256 * 2);
    float*  dinv = (float*)alloc((size_t)N * 4);
    float*  gbuf = (float*)alloc((size_t)G * 128 * 4);
    int* cnt   = (int*)alloc((size_t)N * 4);
    int* offs  = (int*)alloc((size_t)(N + 1) * 4);
    int* cur   = (int*)alloc((size_t)N * 4);
    int* elist = (int*)alloc((size_t)E * 4);

    hipMemsetAsync(cnt, 0, (size_t)N * sizeof(int), stream);
    hipMemsetAsync(cur, 0, (size_t)N * sizeof(int), stream);
    hipMemsetAsync(gbuf, 0, (size_t)G * 128 * sizeof(float), stream);

    // CSR + degree norm
    count_kernel<<<HGRID(E, 256), 256, 0, stream>>>(dstv, cnt, E);
    scan_kernel<<<1, 1024, 0, stream>>>(cnt, offs, N);
    fill_kernel<<<HGRID(E, 256), 256, 0, stream>>>(srcv, dstv, offs, cur, elist, E);
    dinv_kernel<<<HGRID(N, 256), 256, 0, stream>>>(cnt, dinv, N);

    // input + weight conversion to bf16 (weights transposed + K-padded)
    f2b_kernel<<<HGRID((size_t)N * 128 / 4, 256), 256, 0, stream>>>(x, xb, (long)N * 128);
    f2b_kernel<<<HGRID((size_t)N * 16 / 4, 256), 256, 0, stream>>>(s_in, sb, (long)N * 16);
    twb_kernel<<<HGRID(128 * 128, 256), 256, 0, stream>>>(pre_w, Wt_pre, 128, 128);
    twb_kernel<<<HGRID(128 * 32, 256), 256, 0, stream>>>(emb_w, Wt_emb, 16, 32);
    for (int i = 0; i < L; ++i) {
        twb_kernel<<<HGRID(128 * 256, 256), 256, 0, stream>>>(
            gin_w1 + (size_t)i * 256 * 128, Wt_gin1 + (size_t)i * 128 * 256, 256, 256);
        twb_kernel<<<HGRID(128 * 128, 256), 256, 0, stream>>>(
            gin_w2 + (size_t)i * 128 * 128, Wt_gin2 + (size_t)i * 128 * 128, 128, 128);
        twb_kernel<<<HGRID(128 * 128, 256), 256, 0, stream>>>(
            gcn_w + (size_t)i * 128 * 128, Wt_gcn + (size_t)i * 128 * 128, 128, 128);
    }
    twb_kernel<<<HGRID(128 * 256, 256), 256, 0, stream>>>(whp_w, Wt_whp, 256, 256);

    const int lb = HGRID(N, 64);
    // pre / embedding into xc = [x | s]
    linear_mfma<128><<<lb, 128, 0, stream>>>(xb, 128, 128, Wt_pre, pre_b, xc, 256, N, 0);
    linear_mfma<32><<<lb, 128, 0, stream>>>(sb, 16, 16, Wt_emb, emb_b, xc + 128, 256, N, 0);

    for (int i = 0; i < L; ++i) {
        linear_mfma<256><<<lb, 128, 0, stream>>>(xc, 256, 256,
            Wt_gin1 + (size_t)i * 128 * 256, nullptr, y, 128, N, 0);
        linear_mfma<128><<<lb, 128, 0, stream>>>(xc + 128, 256, 128,
            Wt_gcn + (size_t)i * 128 * 128, nullptr, hs, 128, N, 0);
        fused_gather<<<HGRID(N, 4), 256, 0, stream>>>(
            (const uint*)y, (const uint*)hs, offs, elist, dinv,
            gin_b1 + (size_t)i * H, gcn_b + (size_t)i * H,
            (uint*)h1, (uint*)xc, N);
        linear_mfma<128><<<lb, 128, 0, stream>>>(h1, 128, 128,
            Wt_gin2 + (size_t)i * 128 * 128, gin_b2 + (size_t)i * H, xc, 256, N, 1);
    }

    // whp projection (into y, free now)
    linear_mfma<256><<<lb, 128, 0, stream>>>(xc, 256, 256, Wt_whp, whp_b, y, 128, N, 0);

    pool_kernel<<<HGRID(N, 128), 128, 0, stream>>>(y, batch, gbuf, N);
    head_kernel<<<G, 128, 0, stream>>>(gbuf, post_w, post_b, ro_w, ro_b, (float*)d_out, C);
}

// Round 3
// 579.431 us; speedup vs baseline: 4.4881x; 1.2619x over previous
//
#include <hip/hip_runtime.h>
#include <math.h>

typedef __attribute__((ext_vector_type(8))) short short8;
typedef __attribute__((ext_vector_type(4))) float f32x4;
typedef unsigned int uint;
typedef unsigned short ushort;

#define HGRID(n, b) (((n) + (b) - 1) / (b))

__device__ __forceinline__ ushort f2bu(float f) {
    uint x = __builtin_bit_cast(uint, f);
    x = (x + 0x7fffu + ((x >> 16) & 1u)) >> 16;
    return (ushort)x;
}
__device__ __forceinline__ float bu2f(uint u) {
    return __builtin_bit_cast(float, u << 16);
}
__device__ __forceinline__ uint packbf(float a, float b) {
    return (uint)f2bu(a) | ((uint)f2bu(b) << 16);
}

// ---------------- init (replaces 3 memsets) ----------------

__global__ void init_kernel(int* __restrict__ cnt, int* __restrict__ cur,
                            float* __restrict__ gbuf, int N, int GH) {
    int i = blockIdx.x * 256 + threadIdx.x;
    if (i < N) { cnt[i] = 0; cur[i] = 0; }
    if (i < GH) gbuf[i] = 0.f;
}

// ---------------- CSR build ----------------

__global__ void count_kernel(const int* __restrict__ dst, int* __restrict__ cnt, int E) {
    int e = blockIdx.x * 256 + threadIdx.x;
    if (e < E) atomicAdd(&cnt[dst[e]], 1);
}

__global__ void scan_kernel(const int* __restrict__ cnt, int* __restrict__ offs, int N) {
    __shared__ int sh[1024];
    int t = threadIdx.x;
    int chunk = (N + 1023) >> 10;
    int lo = t * chunk;
    int hi = min(lo + chunk, N);
    int s = 0;
    for (int i = lo; i < hi; ++i) s += cnt[i];
    sh[t] = s;
    __syncthreads();
    for (int d = 1; d < 1024; d <<= 1) {
        int v = (t >= d) ? sh[t - d] : 0;
        __syncthreads();
        sh[t] += v;
        __syncthreads();
    }
    int run = (t == 0) ? 0 : sh[t - 1];
    for (int i = lo; i < hi; ++i) { offs[i] = run; run += cnt[i]; }
    if (t == 1023) offs[N] = sh[1023];
}

// fill elist + dinv in one launch (cnt is final after count_kernel)
__global__ void fill_dinv_kernel(const int* __restrict__ src, const int* __restrict__ dst,
                                 const int* __restrict__ offs, int* __restrict__ cur,
                                 int* __restrict__ elist, const int* __restrict__ cnt,
                                 float* __restrict__ dinv, int E, int N) {
    int e = blockIdx.x * 256 + threadIdx.x;
    if (e < N) dinv[e] = rsqrtf((float)cnt[e] + 1.0f);
    if (e < E) {
        int d = dst[e];
        int p = offs[d] + atomicAdd(&cur[d], 1);
        elist[p] = src[e];
    }
}

// ---------------- input conversion: xs[N][192] = [x bf16 | s bf16 | 0 pad] ----------------

__global__ void conv_in(const float* __restrict__ x, const float* __restrict__ s,
                        ushort* __restrict__ xs, int N) {
    long idx = (long)blockIdx.x * 256 + threadIdx.x;
    if (idx >= (long)N * 192) return;
    int n = (int)(idx / 192), k = (int)(idx % 192);
    float v = 0.f;
    if (k < 128) v = x[(long)n * 128 + k];
    else if (k < 144) v = s[(long)n * 16 + (k - 128)];
    xs[idx] = f2bu(v);
}

// ---------------- all weight transposes in one launch ----------------
// Wt layouts: [out_col][K] bf16, zero-padded.
// Wt_preemb[256][192]: cols 0-127 <- pre_w (k<128); cols 128-255 <- emb_w (k 128-143)
// Wt_dual[i][256][256]: cols 0-127 <- gin_w1[i]; cols 128-255 <- gcn_w[i] (k 128-255)
// Wt_gin2[i][128][128], Wt_whp[128][256]: plain transpose
struct WtArgs {
    const float *pre_w, *pre_b, *emb_w, *emb_b, *gin_w1, *gcn_w, *gin_w2, *whp_w;
    ushort *Wt_preemb, *Wt_dual, *Wt_gin2, *Wt_whp;
    float *bias_comb;
    int L;
};

__global__ void twb_all(WtArgs a) {
    long idx = (long)blockIdx.x * 256 + threadIdx.x;
    if (idx < 49152) {
        int c = (int)(idx / 192), k = (int)(idx % 192);
        float v = 0.f;
        if (c < 128) { if (k < 128) v = a.pre_w[(long)k * 128 + c]; }
        else if (k >= 128 && k < 144) v = a.emb_w[(long)(k - 128) * 128 + (c - 128)];
        a.Wt_preemb[idx] = f2bu(v);
        return;
    }
    idx -= 49152;
    if (idx < (long)a.L * 65536) {
        int i = (int)(idx / 65536);
        int r = (int)(idx % 65536);
        int c = r / 256, k = r % 256;
        float v = 0.f;
        if (c < 128) v = a.gin_w1[(long)i * 32768 + (long)k * 128 + c];
        else if (k >= 128) v = a.gcn_w[(long)i * 16384 + (long)(k - 128) * 128 + (c - 128)];
        a.Wt_dual[idx] = f2bu(v);
        return;
    }
    idx -= (long)a.L * 65536;
    if (idx < (long)a.L * 16384) {
        int i = (int)(idx / 16384);
        int r = (int)(idx % 16384);
        int c = r / 128, k = r % 128;
        a.Wt_gin2[idx] = f2bu(a.gin_w2[(long)i * 16384 + (long)k * 128 + c]);
        return;
    }
    idx -= (long)a.L * 16384;
    if (idx < 32768) {
        int c = (int)(idx / 256), k = (int)(idx % 256);
        a.Wt_whp[idx] = f2bu(a.whp_w[(long)k * 128 + c]);
        return;
    }
    idx -= 32768;
    if (idx < 256) a.bias_comb[idx] = (idx < 128) ? a.pre_b[idx] : a.emb_b[idx - 128];
}

// ---------------- unified MFMA linear ----------------
// out[N][BN] = A[N,KPAD] @ Wt^T, A bf16 (stride a_stride), Wt [BN][KPAD] bf16.
// BM=64 rows/block, 4 waves, wave w owns cols [w*BN/4, (w+1)*BN/4).
// T2 XOR-swizzled LDS (stride=BK, chunk^=(row&7)) -> ~2-way conflicts.
// interleaved=1: write yh layout (y ch c -> ushort 4*(c>>1)+(c&1); h -> +2).

template<int KPAD, int BN>
__global__ __launch_bounds__(256) void lin_mfma(
    const ushort* __restrict__ A, int a_stride,
    const ushort* __restrict__ Wt, const float* __restrict__ bias,
    ushort* __restrict__ out, int o_stride, int N, int act, int interleaved)
{
    constexpr int BK = 64;
    constexpr int NF = BN / 64;    // col-frags per wave
    __shared__ __align__(16) ushort LA[64][BK];
    __shared__ __align__(16) ushort LB[BN][BK];

    const int tid  = threadIdx.x;
    const int l    = tid & 63;
    const int w    = tid >> 6;
    const int row0 = blockIdx.x * 64;
    const int l15  = l & 15;
    const int lhi  = l >> 4;

    f32x4 acc[4][NF];
    #pragma unroll
    for (int m = 0; m < 4; ++m)
        #pragma unroll
        for (int n = 0; n < NF; ++n) acc[m][n] = (f32x4){0.f, 0.f, 0.f, 0.f};

    for (int k0 = 0; k0 < KPAD; k0 += BK) {
        __syncthreads();
        #pragma unroll
        for (int it = 0; it < 2; ++it) {           // A: 64 rows x 8 chunks
            int idx = it * 256 + tid;
            int r = idx >> 3, ch = idx & 7;
            int gr = row0 + r;
            uint4 v = {0u, 0u, 0u, 0u};
            if (gr < N) v = *(const uint4*)(A + (long)gr * a_stride + k0 + ch * 8);
            *(uint4*)&LA[r][(ch ^ (r & 7)) * 8] = v;
        }
        #pragma unroll
        for (int it = 0; it < BN / 32; ++it) {     // B: BN rows x 8 chunks
            int idx = it * 256 + tid;
            int c = idx >> 3, ch = idx & 7;
            uint4 v = *(const uint4*)(Wt + (long)c * KPAD + k0 + ch * 8);
            *(uint4*)&LB[c][(ch ^ (c & 7)) * 8] = v;
        }
        __syncthreads();
        #pragma unroll
        for (int kk = 0; kk < BK; kk += 32) {
            int chb = (kk >> 3) + lhi;
            short8 a[4];
            #pragma unroll
            for (int m = 0; m < 4; ++m) {
                int r = m * 16 + l15;
                a[m] = *(const short8*)&LA[r][(chb ^ (r & 7)) * 8];
            }
            #pragma unroll
            for (int n = 0; n < NF; ++n) {
                int c = w * (NF * 16) + n * 16 + l15;
                short8 b = *(const short8*)&LB[c][(chb ^ (c & 7)) * 8];
                #pragma unroll
                for (int m = 0; m < 4; ++m)
                    acc[m][n] = __builtin_amdgcn_mfma_f32_16x16x32_bf16(a[m], b, acc[m][n], 0, 0, 0);
            }
        }
    }

    #pragma unroll
    for (int n = 0; n < NF; ++n) {
        int col = w * (NF * 16) + n * 16 + l15;
        float bv = bias ? bias[col] : 0.f;
        #pragma unroll
        for (int m = 0; m < 4; ++m) {
            #pragma unroll
            for (int j = 0; j < 4; ++j) {
                int gr = row0 + m * 16 + (lhi << 2) + j;
                if (gr < N) {
                    float v = acc[m][n][j] + bv;
                    if (act) v = fmaxf(v, 0.f);
                    long off;
                    if (interleaved) {
                        int cc = col & 127;
                        off = (long)gr * 256 + 4 * (cc >> 1) + ((col >> 7) << 1) + (cc & 1);
                    } else {
                        off = (long)gr * o_stride + col;
                    }
                    out[off] = f2bu(v);
                }
            }
        }
    }
}

// ---------------- fused GIN+GCN gather (wave/node, interleaved yh, unroll-4) ----------------
// yh[n] row: per lane l, uint2 {y ch(2l,2l+1), hs ch(2l,2l+1)}
// h1[n]   = relu(y[n] + sum_s y[s] + b1)
// xc_s[n] = tanh(di*sum_s hs[s]*dinv[s] + hs[n]*di^2 + gcn_b)

__global__ __launch_bounds__(256) void fused_gather(
    const uint2* __restrict__ yh, const int* __restrict__ offs,
    const int* __restrict__ elist, const float* __restrict__ dinv,
    const float* __restrict__ b1, const float* __restrict__ gb,
    uint* __restrict__ h1p, uint* __restrict__ xcp, int N)
{
    int node = blockIdx.x * 4 + (threadIdx.x >> 6);
    if (node >= N) return;
    int l = threadIdx.x & 63;

    uint2 self = yh[(long)node * 64 + l];
    float di = dinv[node];
    float g0 = bu2f(self.x & 0xffffu), g1 = bu2f(self.x >> 16);
    float s0 = 0.f, s1 = 0.f;

    int j = offs[node], j1 = offs[node + 1];
    for (; j + 3 < j1; j += 4) {
        int sa = elist[j], sb = elist[j + 1], sc = elist[j + 2], sd = elist[j + 3];
        uint2 va = yh[(long)sa * 64 + l];
        uint2 vb = yh[(long)sb * 64 + l];
        uint2 vc = yh[(long)sc * 64 + l];
        uint2 vd = yh[(long)sd * 64 + l];
        float da = dinv[sa], db = dinv[sb], dc = dinv[sc], dd = dinv[sd];
        g0 += bu2f(va.x & 0xffffu) + bu2f(vb.x & 0xffffu) + bu2f(vc.x & 0xffffu) + bu2f(vd.x & 0xffffu);
        g1 += bu2f(va.x >> 16)     + bu2f(vb.x >> 16)     + bu2f(vc.x >> 16)     + bu2f(vd.x >> 16);
        s0 += bu2f(va.y & 0xffffu) * da + bu2f(vb.y & 0xffffu) * db
            + bu2f(vc.y & 0xffffu) * dc + bu2f(vd.y & 0xffffu) * dd;
        s1 += bu2f(va.y >> 16) * da + bu2f(vb.y >> 16) * db
            + bu2f(vc.y >> 16) * dc + bu2f(vd.y >> 16) * dd;
    }
    for (; j < j1; ++j) {
        int sa = elist[j];
        uint2 va = yh[(long)sa * 64 + l];
        float da = dinv[sa];
        g0 += bu2f(va.x & 0xffffu);
        g1 += bu2f(va.x >> 16);
        s0 += bu2f(va.y & 0xffffu) * da;
        s1 += bu2f(va.y >> 16) * da;
    }

    float2 bb = ((const float2*)b1)[l];
    g0 = fmaxf(g0 + bb.x, 0.f);
    g1 = fmaxf(g1 + bb.y, 0.f);
    h1p[(long)node * 64 + l] = packbf(g0, g1);

    float dii = di * di;
    float2 gg = ((const float2*)gb)[l];
    float t0 = tanhf(s0 * di + bu2f(self.y & 0xffffu) * dii + gg.x);
    float t1 = tanhf(s1 * di + bu2f(self.y >> 16) * dii + gg.y);
    xcp[(long)node * 128 + 64 + l] = packbf(t0, t1);
}

// ---------------- pooling (batch sorted, bf16 input, fp32 atomics) ----------------

__global__ void pool_kernel(const ushort* __restrict__ xh, const int* __restrict__ batch,
                            float* __restrict__ g, int N) {
    int c  = threadIdx.x;        // 128
    int n0 = blockIdx.x * 128;
    if (n0 >= N) return;
    int n1 = min(n0 + 128, N);
    int curg = batch[n0];
    float acc = 0.f;
    for (int n = n0; n < n1; ++n) {
        int b = batch[n];
        if (b != curg) {
            atomicAdd(&g[(long)curg * 128 + c], acc);
            acc = 0.f;
            curg = b;
        }
        acc += bu2f((uint)xh[(long)n * 128 + c]);
    }
    atomicAdd(&g[(long)curg * 128 + c], acc);
}

// ---------------- head ----------------

__global__ void head_kernel(const float* __restrict__ g, const float* __restrict__ post_w,
                            const float* __restrict__ post_b, const float* __restrict__ ro_w,
                            const float* __restrict__ ro_b, float* __restrict__ out, int C) {
    __shared__ float row[128];
    __shared__ float g2[128];
    __shared__ float lg[16];
    __shared__ float s_lse;
    int gi = blockIdx.x;
    int c  = threadIdx.x;   // 128
    row[c] = g[(long)gi * 128 + c];
    __syncthreads();
    float acc = post_b[c];
    for (int k = 0; k < 128; ++k) acc += row[k] * post_w[k * 128 + c];
    g2[c] = fmaxf(acc, 0.f);
    __syncthreads();
    if (c < C) {
        float a = ro_b[c];
        for (int k = 0; k < 128; ++k) a += g2[k] * ro_w[k * C + c];
        lg[c] = a;
    }
    __syncthreads();
    if (c == 0) {
        float m = lg[0];
        for (int i = 1; i < C; ++i) m = fmaxf(m, lg[i]);
        float sum = 0.f;
        for (int i = 0; i < C; ++i) sum += expf(lg[i] - m);
        s_lse = m + logf(sum);
    }
    __syncthreads();
    if (c < C) out[(long)gi * C + c] = lg[c] - s_lse;
}

// ---------------- launch ----------------

extern "C" void kernel_launch(void* const* d_in, const int* in_sizes, int n_in,
                              void* d_out, int out_size, void* d_ws, size_t ws_size,
                              hipStream_t stream) {
    const float* x      = (const float*)d_in[0];
    const float* s_in   = (const float*)d_in[1];
    const int*   ei     = (const int*)d_in[2];
    const int*   batch  = (const int*)d_in[3];
    const float* pre_w  = (const float*)d_in[4];
    const float* pre_b  = (const float*)d_in[5];
    const float* emb_w  = (const float*)d_in[6];
    const float* emb_b  = (const float*)d_in[7];
    const float* gin_w1 = (const float*)d_in[8];
    const float* gin_b1 = (const float*)d_in[9];
    const float* gin_w2 = (const float*)d_in[10];
    const float* gin_b2 = (const float*)d_in[11];
    const float* gcn_w  = (const float*)d_in[12];
    const float* gcn_b  = (const float*)d_in[13];
    const float* whp_w  = (const float*)d_in[14];
    const float* whp_b  = (const float*)d_in[15];
    const float* post_w = (const float*)d_in[16];
    const float* post_b = (const float*)d_in[17];
    const float* ro_w   = (const float*)d_in[18];
    const float* ro_b   = (const float*)d_in[19];

    const int H = 128;
    const int N = in_sizes[0] / 128;
    const int E = in_sizes[2] / 2;
    const int C = in_sizes[19];
    const int G = out_size / C;
    const int L = in_sizes[9] / H;

    const int* srcv = ei;
    const int* dstv = ei + E;

    // ---- workspace layout ----
    char* p = (char*)d_ws;
    auto alloc = [&](size_t bytes) -> void* {
        void* r = (void*)p;
        p += (bytes + 255) & ~(size_t)255;
        return r;
    };
    ushort* xc   = (ushort*)alloc((size_t)N * 256 * 2);   // [N][256] = [x | s] plain
    ushort* yh   = (ushort*)alloc((size_t)N * 256 * 2);   // [N][256] interleaved y/hs
    ushort* h1   = (ushort*)alloc((size_t)N * 128 * 2);
    ushort* xs   = (ushort*)alloc((size_t)N * 192 * 2);   // [x|s|pad] bf16
    ushort* ybuf = (ushort*)alloc((size_t)N * 128 * 2);   // whp output
    ushort* Wt_preemb = (ushort*)alloc(256 * 192 * 2);
    ushort* Wt_dual   = (ushort*)alloc((size_t)L * 256 * 256 * 2);
    ushort* Wt_gin2   = (ushort*)alloc((size_t)L * 128 * 128 * 2);
    ushort* Wt_whp    = (ushort*)alloc(128 * 256 * 2);
    float*  bias_comb = (float*)alloc(256 * 4);
    float*  dinv = (float*)alloc((size_t)N * 4);
    float*  gbuf = (float*)alloc((size_t)G * 128 * 4);
    int* cnt   = (int*)alloc((size_t)N * 4);
    int* offs  = (int*)alloc((size_t)(N + 1) * 4);
    int* cur   = (int*)alloc((size_t)N * 4);
    int* elist = (int*)alloc((size_t)E * 4);

    init_kernel<<<HGRID(N, 256), 256, 0, stream>>>(cnt, cur, gbuf, N, G * 128);
    count_kernel<<<HGRID(E, 256), 256, 0, stream>>>(dstv, cnt, E);
    scan_kernel<<<1, 1024, 0, stream>>>(cnt, offs, N);
    fill_dinv_kernel<<<HGRID(E, 256), 256, 0, stream>>>(srcv, dstv, offs, cur, elist,
                                                        cnt, dinv, E, N);
    conv_in<<<HGRID((long)N * 192, 256), 256, 0, stream>>>(x, s_in, xs, N);

    WtArgs wa;
    wa.pre_w = pre_w; wa.pre_b = pre_b; wa.emb_w = emb_w; wa.emb_b = emb_b;
    wa.gin_w1 = gin_w1; wa.gcn_w = gcn_w; wa.gin_w2 = gin_w2; wa.whp_w = whp_w;
    wa.Wt_preemb = Wt_preemb; wa.Wt_dual = Wt_dual; wa.Wt_gin2 = Wt_gin2;
    wa.Wt_whp = Wt_whp; wa.bias_comb = bias_comb; wa.L = L;
    long twb_tot = 49152 + (long)L * 65536 + (long)L * 16384 + 32768 + 256;
    twb_all<<<HGRID(twb_tot, 256), 256, 0, stream>>>(wa);

    const int lb = HGRID(N, 64);
    // xc = [pre(x) | emb(s)]  (plain layout)
    lin_mfma<192, 256><<<lb, 256, 0, stream>>>(xs, 192, Wt_preemb, bias_comb,
                                               xc, 256, N, 0, 0);

    for (int i = 0; i < L; ++i) {
        // yh = interleave(xc@gin_w1, s@gcn_w)
        lin_mfma<256, 256><<<lb, 256, 0, stream>>>(xc, 256, Wt_dual + (size_t)i * 65536,
                                                   nullptr, yh, 256, N, 0, 1);
        fused_gather<<<HGRID(N, 4), 256, 0, stream>>>(
            (const uint2*)yh, offs, elist, dinv,
            gin_b1 + (size_t)i * H, gcn_b + (size_t)i * H,
            (uint*)h1, (uint*)xc, N);
        // xc x-half = relu(h1 @ gin_w2 + b2)
        lin_mfma<128, 128><<<lb, 256, 0, stream>>>(h1, 128, Wt_gin2 + (size_t)i * 16384,
                                                   gin_b2 + (size_t)i * H, xc, 256, N, 1, 0);
    }

    // ybuf = xc @ whp_w + whp_b
    lin_mfma<256, 128><<<lb, 256, 0, stream>>>(xc, 256, Wt_whp, whp_b, ybuf, 128, N, 0, 0);

    pool_kernel<<<HGRID(N, 128), 128, 0, stream>>>(ybuf, batch, gbuf, N);
    head_kernel<<<G, 128, 0, stream>>>(gbuf, post_w, post_b, ro_w, ro_b, (float*)d_out, C);
}

// Round 4
// 507.447 us; speedup vs baseline: 5.1247x; 1.1419x over previous
//
#include <hip/hip_runtime.h>
#include <math.h>

typedef __attribute__((ext_vector_type(8))) short short8;
typedef __attribute__((ext_vector_type(4))) float f32x4;
typedef unsigned int uint;
typedef unsigned short ushort;

#define HGRID(n, b) (((n) + (b) - 1) / (b))

__device__ __forceinline__ ushort f2bu(float f) {
    uint x = __builtin_bit_cast(uint, f);
    x = (x + 0x7fffu + ((x >> 16) & 1u)) >> 16;
    return (ushort)x;
}
__device__ __forceinline__ float bu2f(uint u) {
    return __builtin_bit_cast(float, u << 16);
}
__device__ __forceinline__ uint packbf(float a, float b) {
    return (uint)f2bu(a) | ((uint)f2bu(b) << 16);
}

// ---------------- init ----------------

__global__ void init_kernel(int* __restrict__ cnt, int* __restrict__ cur,
                            float* __restrict__ gbuf, int N, int GH) {
    int i = blockIdx.x * 256 + threadIdx.x;
    if (i < N) { cnt[i] = 0; cur[i] = 0; }
    if (i < GH) gbuf[i] = 0.f;
}

// ---------------- CSR build ----------------

__global__ void count_kernel(const int* __restrict__ dst, int* __restrict__ cnt, int E) {
    int e = blockIdx.x * 256 + threadIdx.x;
    if (e < E) atomicAdd(&cnt[dst[e]], 1);
}

// phase 1: per-block (1024-elem span) sums
__global__ void scan_part(const int* __restrict__ cnt, int* __restrict__ bsum, int N) {
    __shared__ int sh[256];
    int b = blockIdx.x, t = threadIdx.x;
    int base = b * 1024 + t * 4;
    int tsum = 0;
    if (base + 3 < N) {
        int4 v = *(const int4*)(cnt + base);
        tsum = v.x + v.y + v.z + v.w;
    } else {
        #pragma unroll
        for (int k = 0; k < 4; ++k) if (base + k < N) tsum += cnt[base + k];
    }
    sh[t] = tsum;
    __syncthreads();
    for (int d = 128; d > 0; d >>= 1) {
        if (t < d) sh[t] += sh[t + d];
        __syncthreads();
    }
    if (t == 0) bsum[b] = sh[0];
}

// phase 2: exclusive scan of block sums (nb <= 256), writes offs[N] = total
__global__ void scan_top(int* __restrict__ bsum, int* __restrict__ offs, int nb, int N) {
    __shared__ int sh[256];
    int t = threadIdx.x;
    int v = (t < nb) ? bsum[t] : 0;
    sh[t] = v;
    __syncthreads();
    for (int d = 1; d < 256; d <<= 1) {
        int o = (t >= d) ? sh[t - d] : 0;
        __syncthreads();
        sh[t] += o;
        __syncthreads();
    }
    if (t < nb) bsum[t] = sh[t] - v;
    if (t == 255) offs[N] = sh[255];
}

// phase 3: per-block exclusive scan + base; also dinv = rsqrt(cnt+1)
__global__ void scan_fill(const int* __restrict__ cnt, const int* __restrict__ bsum,
                          int* __restrict__ offs, float* __restrict__ dinv, int N) {
    __shared__ int sh[256];
    int b = blockIdx.x, t = threadIdx.x;
    int base = b * 1024 + t * 4;
    int c[4] = {0, 0, 0, 0};
    if (base + 3 < N) {
        int4 v = *(const int4*)(cnt + base);
        c[0] = v.x; c[1] = v.y; c[2] = v.z; c[3] = v.w;
    } else {
        #pragma unroll
        for (int k = 0; k < 4; ++k) if (base + k < N) c[k] = cnt[base + k];
    }
    int tsum = c[0] + c[1] + c[2] + c[3];
    sh[t] = tsum;
    __syncthreads();
    for (int d = 1; d < 256; d <<= 1) {
        int o = (t >= d) ? sh[t - d] : 0;
        __syncthreads();
        sh[t] += o;
        __syncthreads();
    }
    int run = bsum[b] + sh[t] - tsum;
    #pragma unroll
    for (int k = 0; k < 4; ++k) {
        if (base + k < N) {
            offs[base + k] = run;
            dinv[base + k] = rsqrtf((float)c[k] + 1.0f);
            run += c[k];
        }
    }
}

// fill edge records {src, dinv[src]} grouped by dst
__global__ void fill_kernel(const int* __restrict__ src, const int* __restrict__ dst,
                            const int* __restrict__ offs, int* __restrict__ cur,
                            const float* __restrict__ dinv, int2* __restrict__ epack, int E) {
    int e = blockIdx.x * 256 + threadIdx.x;
    if (e < E) {
        int d = dst[e];
        int sv = src[e];
        int p = offs[d] + atomicAdd(&cur[d], 1);
        epack[p] = make_int2(sv, __float_as_int(dinv[sv]));
    }
}

// ---------------- input conversion: xs[N][192] = [x bf16 | s bf16 | 0 pad] ----------------
// one uint4 (8 bf16) per thread; 24 chunks per row

__global__ void conv_in(const float* __restrict__ x, const float* __restrict__ s,
                        ushort* __restrict__ xs, int N) {
    long idx = (long)blockIdx.x * 256 + threadIdx.x;
    if (idx >= (long)N * 24) return;
    int n = (int)(idx / 24), ch = (int)(idx % 24);
    uint4 o = {0u, 0u, 0u, 0u};
    if (ch < 16) {
        const float4* px = (const float4*)(x + (long)n * 128 + ch * 8);
        float4 a = px[0], b = px[1];
        o.x = packbf(a.x, a.y); o.y = packbf(a.z, a.w);
        o.z = packbf(b.x, b.y); o.w = packbf(b.z, b.w);
    } else if (ch < 18) {
        const float4* ps = (const float4*)(s + (long)n * 16 + (ch - 16) * 8);
        float4 a = ps[0], b = ps[1];
        o.x = packbf(a.x, a.y); o.y = packbf(a.z, a.w);
        o.z = packbf(b.x, b.y); o.w = packbf(b.z, b.w);
    }
    *(uint4*)(xs + idx * 8) = o;
}

// ---------------- all weight transposes in one launch ----------------

struct WtArgs {
    const float *pre_w, *pre_b, *emb_w, *emb_b, *gin_w1, *gcn_w, *gin_w2, *whp_w;
    ushort *Wt_preemb, *Wt_dual, *Wt_gin2, *Wt_whp;
    float *bias_comb;
    int L;
};

__global__ void twb_all(WtArgs a) {
    long idx = (long)blockIdx.x * 256 + threadIdx.x;
    if (idx < 49152) {
        int c = (int)(idx / 192), k = (int)(idx % 192);
        float v = 0.f;
        if (c < 128) { if (k < 128) v = a.pre_w[(long)k * 128 + c]; }
        else if (k >= 128 && k < 144) v = a.emb_w[(long)(k - 128) * 128 + (c - 128)];
        a.Wt_preemb[idx] = f2bu(v);
        return;
    }
    idx -= 49152;
    if (idx < (long)a.L * 65536) {
        int i = (int)(idx / 65536);
        int r = (int)(idx % 65536);
        int c = r / 256, k = r % 256;
        float v = 0.f;
        if (c < 128) v = a.gin_w1[(long)i * 32768 + (long)k * 128 + c];
        else if (k >= 128) v = a.gcn_w[(long)i * 16384 + (long)(k - 128) * 128 + (c - 128)];
        a.Wt_dual[idx] = f2bu(v);
        return;
    }
    idx -= (long)a.L * 65536;
    if (idx < (long)a.L * 16384) {
        int i = (int)(idx / 16384);
        int r = (int)(idx % 16384);
        int c = r / 128, k = r % 128;
        a.Wt_gin2[idx] = f2bu(a.gin_w2[(long)i * 16384 + (long)k * 128 + c]);
        return;
    }
    idx -= (long)a.L * 16384;
    if (idx < 32768) {
        int c = (int)(idx / 256), k = (int)(idx % 256);
        a.Wt_whp[idx] = f2bu(a.whp_w[(long)k * 128 + c]);
        return;
    }
    idx -= 32768;
    if (idx < 256) a.bias_comb[idx] = (idx < 128) ? a.pre_b[idx] : a.emb_b[idx - 128];
}

// ---------------- unified MFMA linear ----------------

template<int KPAD, int BN>
__global__ __launch_bounds__(256) void lin_mfma(
    const ushort* __restrict__ A, int a_stride,
    const ushort* __restrict__ Wt, const float* __restrict__ bias,
    ushort* __restrict__ out, int o_stride, int N, int act, int interleaved)
{
    constexpr int BK = 64;
    constexpr int NF = BN / 64;
    __shared__ __align__(16) ushort LA[64][BK];
    __shared__ __align__(16) ushort LB[BN][BK];

    const int tid  = threadIdx.x;
    const int l    = tid & 63;
    const int w    = tid >> 6;
    const int row0 = blockIdx.x * 64;
    const int l15  = l & 15;
    const int lhi  = l >> 4;

    f32x4 acc[4][NF];
    #pragma unroll
    for (int m = 0; m < 4; ++m)
        #pragma unroll
        for (int n = 0; n < NF; ++n) acc[m][n] = (f32x4){0.f, 0.f, 0.f, 0.f};

    for (int k0 = 0; k0 < KPAD; k0 += BK) {
        __syncthreads();
        #pragma unroll
        for (int it = 0; it < 2; ++it) {
            int idx = it * 256 + tid;
            int r = idx >> 3, ch = idx & 7;
            int gr = row0 + r;
            uint4 v = {0u, 0u, 0u, 0u};
            if (gr < N) v = *(const uint4*)(A + (long)gr * a_stride + k0 + ch * 8);
            *(uint4*)&LA[r][(ch ^ (r & 7)) * 8] = v;
        }
        #pragma unroll
        for (int it = 0; it < BN / 32; ++it) {
            int idx = it * 256 + tid;
            int c = idx >> 3, ch = idx & 7;
            uint4 v = *(const uint4*)(Wt + (long)c * KPAD + k0 + ch * 8);
            *(uint4*)&LB[c][(ch ^ (c & 7)) * 8] = v;
        }
        __syncthreads();
        #pragma unroll
        for (int kk = 0; kk < BK; kk += 32) {
            int chb = (kk >> 3) + lhi;
            short8 a[4];
            #pragma unroll
            for (int m = 0; m < 4; ++m) {
                int r = m * 16 + l15;
                a[m] = *(const short8*)&LA[r][(chb ^ (r & 7)) * 8];
            }
            #pragma unroll
            for (int n = 0; n < NF; ++n) {
                int c = w * (NF * 16) + n * 16 + l15;
                short8 b = *(const short8*)&LB[c][(chb ^ (c & 7)) * 8];
                #pragma unroll
                for (int m = 0; m < 4; ++m)
                    acc[m][n] = __builtin_amdgcn_mfma_f32_16x16x32_bf16(a[m], b, acc[m][n], 0, 0, 0);
            }
        }
    }

    #pragma unroll
    for (int n = 0; n < NF; ++n) {
        int col = w * (NF * 16) + n * 16 + l15;
        float bv = bias ? bias[col] : 0.f;
        #pragma unroll
        for (int m = 0; m < 4; ++m) {
            #pragma unroll
            for (int j = 0; j < 4; ++j) {
                int gr = row0 + m * 16 + (lhi << 2) + j;
                if (gr < N) {
                    float v = acc[m][n][j] + bv;
                    if (act) v = fmaxf(v, 0.f);
                    long off;
                    if (interleaved) {
                        int cc = col & 127;
                        off = (long)gr * 256 + 4 * (cc >> 1) + ((col >> 7) << 1) + (cc & 1);
                    } else {
                        off = (long)gr * o_stride + col;
                    }
                    out[off] = f2bu(v);
                }
            }
        }
    }
}

// ---------------- fused GIN+GCN gather (wave/node, epack edges, unroll-8) ----------------

__global__ __launch_bounds__(256) void fused_gather(
    const uint2* __restrict__ yh, const int* __restrict__ offs,
    const int2* __restrict__ epack, const float* __restrict__ dinv,
    const float* __restrict__ b1, const float* __restrict__ gb,
    uint* __restrict__ h1p, uint* __restrict__ xcp, int N)
{
    int node = blockIdx.x * 4 + (threadIdx.x >> 6);
    if (node >= N) return;
    int l = threadIdx.x & 63;

    uint2 self = yh[(long)node * 64 + l];
    float di = dinv[node];
    float g0 = bu2f(self.x & 0xffffu), g1 = bu2f(self.x >> 16);
    float s0 = 0.f, s1 = 0.f;

    int j0 = offs[node], j1 = offs[node + 1];
    int jmid = j0 + ((j1 - j0) & ~7);

    for (int j = j0; j < jmid; j += 8) {
        int2 e[8]; uint2 v[8];
        #pragma unroll
        for (int k = 0; k < 8; ++k) e[k] = epack[j + k];
        #pragma unroll
        for (int k = 0; k < 8; ++k) v[k] = yh[(long)e[k].x * 64 + l];
        #pragma unroll
        for (int k = 0; k < 8; ++k) {
            float ds = __int_as_float(e[k].y);
            g0 += bu2f(v[k].x & 0xffffu);
            g1 += bu2f(v[k].x >> 16);
            s0 += bu2f(v[k].y & 0xffffu) * ds;
            s1 += bu2f(v[k].y >> 16) * ds;
        }
    }
    if (jmid < j1) {                       // masked tail batch (keeps 8 loads in flight)
        int2 e[8]; uint2 v[8];
        #pragma unroll
        for (int k = 0; k < 8; ++k) {
            int jj = jmid + k;
            e[k] = epack[(jj < j1) ? jj : (j1 - 1)];
            if (jj >= j1) e[k].y = 0;
        }
        #pragma unroll
        for (int k = 0; k < 8; ++k) v[k] = yh[(long)e[k].x * 64 + l];
        #pragma unroll
        for (int k = 0; k < 8; ++k) {
            float ds = __int_as_float(e[k].y);
            float m = (jmid + k < j1) ? 1.f : 0.f;
            g0 += bu2f(v[k].x & 0xffffu) * m;
            g1 += bu2f(v[k].x >> 16) * m;
            s0 += bu2f(v[k].y & 0xffffu) * ds;
            s1 += bu2f(v[k].y >> 16) * ds;
        }
    }

    float2 bb = ((const float2*)b1)[l];
    g0 = fmaxf(g0 + bb.x, 0.f);
    g1 = fmaxf(g1 + bb.y, 0.f);
    h1p[(long)node * 64 + l] = packbf(g0, g1);

    float dii = di * di;
    float2 gg = ((const float2*)gb)[l];
    float t0 = tanhf(s0 * di + bu2f(self.y & 0xffffu) * dii + gg.x);
    float t1 = tanhf(s1 * di + bu2f(self.y >> 16) * dii + gg.y);
    xcp[(long)node * 128 + 64 + l] = packbf(t0, t1);
}

// ---------------- pooling ----------------

__global__ void pool_kernel(const ushort* __restrict__ xh, const int* __restrict__ batch,
                            float* __restrict__ g, int N) {
    int c  = threadIdx.x;
    int n0 = blockIdx.x * 128;
    if (n0 >= N) return;
    int n1 = min(n0 + 128, N);
    int curg = batch[n0];
    float acc = 0.f;
    for (int n = n0; n < n1; ++n) {
        int b = batch[n];
        if (b != curg) {
            atomicAdd(&g[(long)curg * 128 + c], acc);
            acc = 0.f;
            curg = b;
        }
        acc += bu2f((uint)xh[(long)n * 128 + c]);
    }
    atomicAdd(&g[(long)curg * 128 + c], acc);
}

// ---------------- head ----------------

__global__ void head_kernel(const float* __restrict__ g, const float* __restrict__ post_w,
                            const float* __restrict__ post_b, const float* __restrict__ ro_w,
                            const float* __restrict__ ro_b, float* __restrict__ out, int C) {
    __shared__ float row[128];
    __shared__ float g2[128];
    __shared__ float lg[16];
    __shared__ float s_lse;
    int gi = blockIdx.x;
    int c  = threadIdx.x;
    row[c] = g[(long)gi * 128 + c];
    __syncthreads();
    float acc = post_b[c];
    for (int k = 0; k < 128; ++k) acc += row[k] * post_w[k * 128 + c];
    g2[c] = fmaxf(acc, 0.f);
    __syncthreads();
    if (c < C) {
        float a = ro_b[c];
        for (int k = 0; k < 128; ++k) a += g2[k] * ro_w[k * C + c];
        lg[c] = a;
    }
    __syncthreads();
    if (c == 0) {
        float m = lg[0];
        for (int i = 1; i < C; ++i) m = fmaxf(m, lg[i]);
        float sum = 0.f;
        for (int i = 0; i < C; ++i) sum += expf(lg[i] - m);
        s_lse = m + logf(sum);
    }
    __syncthreads();
    if (c < C) out[(long)gi * C + c] = lg[c] - s_lse;
}

// ---------------- launch ----------------

extern "C" void kernel_launch(void* const* d_in, const int* in_sizes, int n_in,
                              void* d_out, int out_size, void* d_ws, size_t ws_size,
                              hipStream_t stream) {
    const float* x      = (const float*)d_in[0];
    const float* s_in   = (const float*)d_in[1];
    const int*   ei     = (const int*)d_in[2];
    const int*   batch  = (const int*)d_in[3];
    const float* pre_w  = (const float*)d_in[4];
    const float* pre_b  = (const float*)d_in[5];
    const float* emb_w  = (const float*)d_in[6];
    const float* emb_b  = (const float*)d_in[7];
    const float* gin_w1 = (const float*)d_in[8];
    const float* gin_b1 = (const float*)d_in[9];
    const float* gin_w2 = (const float*)d_in[10];
    const float* gin_b2 = (const float*)d_in[11];
    const float* gcn_w  = (const float*)d_in[12];
    const float* gcn_b  = (const float*)d_in[13];
    const float* whp_w  = (const float*)d_in[14];
    const float* whp_b  = (const float*)d_in[15];
    const float* post_w = (const float*)d_in[16];
    const float* post_b = (const float*)d_in[17];
    const float* ro_w   = (const float*)d_in[18];
    const float* ro_b   = (const float*)d_in[19];

    const int H = 128;
    const int N = in_sizes[0] / 128;
    const int E = in_sizes[2] / 2;
    const int C = in_sizes[19];
    const int G = out_size / C;
    const int L = in_sizes[9] / H;

    const int* srcv = ei;
    const int* dstv = ei + E;

    char* p = (char*)d_ws;
    auto alloc = [&](size_t bytes) -> void* {
        void* r = (void*)p;
        p += (bytes + 255) & ~(size_t)255;
        return r;
    };
    ushort* xc   = (ushort*)alloc((size_t)N * 256 * 2);
    ushort* yh   = (ushort*)alloc((size_t)N * 256 * 2);
    ushort* h1   = (ushort*)alloc((size_t)N * 128 * 2);
    ushort* xs   = (ushort*)alloc((size_t)N * 192 * 2);
    ushort* ybuf = (ushort*)alloc((size_t)N * 128 * 2);
    ushort* Wt_preemb = (ushort*)alloc(256 * 192 * 2);
    ushort* Wt_dual   = (ushort*)alloc((size_t)L * 256 * 256 * 2);
    ushort* Wt_gin2   = (ushort*)alloc((size_t)L * 128 * 128 * 2);
    ushort* Wt_whp    = (ushort*)alloc(128 * 256 * 2);
    float*  bias_comb = (float*)alloc(256 * 4);
    float*  dinv = (float*)alloc((size_t)N * 4);
    float*  gbuf = (float*)alloc((size_t)G * 128 * 4);
    int* cnt   = (int*)alloc((size_t)N * 4);
    int* offs  = (int*)alloc((size_t)(N + 1) * 4);
    int* cur   = (int*)alloc((size_t)N * 4);
    int* bsum  = (int*)alloc((size_t)HGRID(N, 1024) * 4);
    int2* epack = (int2*)alloc((size_t)E * 8);

    const int nb = HGRID(N, 1024);

    init_kernel<<<HGRID(N, 256), 256, 0, stream>>>(cnt, cur, gbuf, N, G * 128);
    count_kernel<<<HGRID(E, 256), 256, 0, stream>>>(dstv, cnt, E);
    scan_part<<<nb, 256, 0, stream>>>(cnt, bsum, N);
    scan_top<<<1, 256, 0, stream>>>(bsum, offs, nb, N);
    scan_fill<<<nb, 256, 0, stream>>>(cnt, bsum, offs, dinv, N);
    fill_kernel<<<HGRID(E, 256), 256, 0, stream>>>(srcv, dstv, offs, cur, dinv, epack, E);
    conv_in<<<HGRID((long)N * 24, 256), 256, 0, stream>>>(x, s_in, xs, N);

    WtArgs wa;
    wa.pre_w = pre_w; wa.pre_b = pre_b; wa.emb_w = emb_w; wa.emb_b = emb_b;
    wa.gin_w1 = gin_w1; wa.gcn_w = gcn_w; wa.gin_w2 = gin_w2; wa.whp_w = whp_w;
    wa.Wt_preemb = Wt_preemb; wa.Wt_dual = Wt_dual; wa.Wt_gin2 = Wt_gin2;
    wa.Wt_whp = Wt_whp; wa.bias_comb = bias_comb; wa.L = L;
    long twb_tot = 49152 + (long)L * 65536 + (long)L * 16384 + 32768 + 256;
    twb_all<<<HGRID(twb_tot, 256), 256, 0, stream>>>(wa);

    const int lb = HGRID(N, 64);
    lin_mfma<192, 256><<<lb, 256, 0, stream>>>(xs, 192, Wt_preemb, bias_comb,
                                               xc, 256, N, 0, 0);

    for (int i = 0; i < L; ++i) {
        lin_mfma<256, 256><<<lb, 256, 0, stream>>>(xc, 256, Wt_dual + (size_t)i * 65536,
                                                   nullptr, yh, 256, N, 0, 1);
        fused_gather<<<HGRID(N, 4), 256, 0, stream>>>(
            (const uint2*)yh, offs, epack, dinv,
            gin_b1 + (size_t)i * H, gcn_b + (size_t)i * H,
            (uint*)h1, (uint*)xc, N);
        lin_mfma<128, 128><<<lb, 256, 0, stream>>>(h1, 128, Wt_gin2 + (size_t)i * 16384,
                                                   gin_b2 + (size_t)i * H, xc, 256, N, 1, 0);
    }

    lin_mfma<256, 128><<<lb, 256, 0, stream>>>(xc, 256, Wt_whp, whp_b, ybuf, 128, N, 0, 0);

    pool_kernel<<<HGRID(N, 128), 128, 0, stream>>>(ybuf, batch, gbuf, N);
    head_kernel<<<G, 128, 0, stream>>>(gbuf, post_w, post_b, ro_w, ro_b, (float*)d_out, C);
}